// Round 1
// baseline (1081.273 us; speedup 1.0000x reference)
//
#include <hip/hip_runtime.h>
#include <cstdint>
#include <cstddef>

#define NN 100000
#define NE 1600000
#define IND 500
#define HD 64
#define OD 40

// ---------- edge loading (int32 vs int64 auto-detect) ----------
static __device__ __forceinline__ int get_edge(const void* ei, int is64, size_t pos) {
    return is64 ? (int)((const long long*)ei)[pos] : ((const int*)ei)[pos];
}

__global__ void k_detect(const unsigned* ei32, int* flags) {
    if (threadIdx.x == 0 && blockIdx.x == 0) {
        int is64 = 1;
        #pragma unroll
        for (int i = 1; i < 16; i += 2)
            if (ei32[i] != 0u) is64 = 0;
        flags[0] = is64;
    }
}

// ---------- degree / norm ----------
__global__ void k_initdeg(float* deg) {
    int i = blockIdx.x * 256 + threadIdx.x;
    if (i < NN) deg[i] = 1.0f;   // self-loop
}

__global__ void k_count(const void* ei, const int* __restrict__ flags, float* deg) {
    int e = blockIdx.x * 256 + threadIdx.x;
    if (e < NE) {
        int d = get_edge(ei, flags[0], (size_t)NE + e);
        atomicAdd(&deg[d], 1.0f);
    }
}

__global__ void k_dinv(float* deg) {
    int i = blockIdx.x * 256 + threadIdx.x;
    if (i < NN) deg[i] = rsqrtf(deg[i]);
}

__global__ void k_norm(const void* ei, const int* __restrict__ flags,
                       const float* __restrict__ dinv, float* __restrict__ norm) {
    int e = blockIdx.x * 256 + threadIdx.x;
    if (e < NE) {
        int is64 = flags[0];
        int s = get_edge(ei, is64, (size_t)e);
        int d = get_edge(ei, is64, (size_t)NE + e);
        norm[e] = dinv[s] * dinv[d];
    }
}

// ---------- GEMM1: h1[100000x64] = x[100000x500] @ W1[500x64] ----------
#define KC 50
__global__ __launch_bounds__(256) void k_gemm1(const float* __restrict__ x,
                                               const float* __restrict__ W,
                                               float* __restrict__ h) {
    __shared__ float xs[KC][68];   // [k][row], stride 68 floats (272 B, 16B-aligned rows)
    __shared__ float wsh[KC][64];  // [k][col]
    const int t = threadIdx.x;
    const int row0 = blockIdx.x * 64;
    const int tx = t & 15;   // col group: cols tx*4 .. tx*4+3
    const int ty = t >> 4;   // row group: rows ty*4 .. ty*4+3
    float acc[4][4];
    #pragma unroll
    for (int i = 0; i < 4; ++i)
        #pragma unroll
        for (int j = 0; j < 4; ++j) acc[i][j] = 0.f;

    for (int kk = 0; kk < IND; kk += KC) {
        // stage x tile: 64 rows x KC cols (coalesced global, transposed into LDS)
        for (int i = t; i < 64 * KC; i += 256) {
            int r = i / KC, k = i - r * KC;
            int grow = row0 + r;
            xs[k][r] = (grow < NN) ? x[(size_t)grow * IND + kk + k] : 0.f;
        }
        // stage W tile: KC x 64 (fully coalesced)
        for (int i = t; i < KC * 64; i += 256) {
            int k = i >> 6, c = i & 63;
            wsh[k][c] = W[(size_t)(kk + k) * HD + c];
        }
        __syncthreads();
        #pragma unroll 10
        for (int k = 0; k < KC; ++k) {
            float4 xv = *(const float4*)&xs[k][ty * 4];
            float4 wv = *(const float4*)&wsh[k][tx * 4];
            float xa[4] = {xv.x, xv.y, xv.z, xv.w};
            float wa[4] = {wv.x, wv.y, wv.z, wv.w};
            #pragma unroll
            for (int i = 0; i < 4; ++i)
                #pragma unroll
                for (int j = 0; j < 4; ++j)
                    acc[i][j] = fmaf(xa[i], wa[j], acc[i][j]);
        }
        __syncthreads();
    }
    #pragma unroll
    for (int i = 0; i < 4; ++i) {
        int grow = row0 + ty * 4 + i;
        if (grow < NN) {
            float4 v = make_float4(acc[i][0], acc[i][1], acc[i][2], acc[i][3]);
            *(float4*)&h[(size_t)grow * HD + tx * 4] = v;
        }
    }
}

// ---------- edge scatter-add (atomics), C = 64 ----------
__global__ void k_agg64(const void* ei, const int* __restrict__ flags,
                        const float* __restrict__ norm,
                        const float* __restrict__ hsrc, float* hdst) {
    long long idx = (long long)blockIdx.x * 256 + threadIdx.x;
    if (idx >= (long long)NE * HD) return;
    int e = (int)(idx >> 6);
    int c = (int)(idx & 63);
    int is64 = flags[0];
    int s = get_edge(ei, is64, (size_t)e);
    int d = get_edge(ei, is64, (size_t)NE + e);
    float v = hsrc[(size_t)s * HD + c] * norm[e];
    atomicAdd(&hdst[(size_t)d * HD + c], v);
}

// ---------- edge scatter-add (atomics), C = 40 ----------
__global__ void k_agg40(const void* ei, const int* __restrict__ flags,
                        const float* __restrict__ norm,
                        const float* __restrict__ hsrc, float* hdst) {
    long long idx = (long long)blockIdx.x * 256 + threadIdx.x;
    if (idx >= (long long)NE * OD) return;
    int e = (int)(idx / OD);
    int c = (int)(idx - (long long)e * OD);
    int is64 = flags[0];
    int s = get_edge(ei, is64, (size_t)e);
    int d = get_edge(ei, is64, (size_t)NE + e);
    float v = hsrc[(size_t)s * OD + c] * norm[e];
    atomicAdd(&hdst[(size_t)d * OD + c], v);
}

// ---------- self-loop + bias + relu (layer 1) ----------
__global__ void k_sb1relu(float* __restrict__ agg, const float* __restrict__ h,
                          const float* __restrict__ dinv, const float* __restrict__ b) {
    int idx = blockIdx.x * 256 + threadIdx.x;
    if (idx < NN * HD) {
        int n = idx >> 6, c = idx & 63;
        float di = dinv[n];
        float v = agg[idx] + h[idx] * di * di + b[c];
        agg[idx] = fmaxf(v, 0.f);
    }
}

// ---------- GEMM2: h2[100000x40] = h1agg[100000x64] @ W2[64x40] ----------
__global__ __launch_bounds__(256) void k_gemm2(const float* __restrict__ h,
                                               const float* __restrict__ W2,
                                               float* __restrict__ h2) {
    __shared__ float hs[32][65];
    __shared__ float ws2[64][40];
    const int t = threadIdx.x;
    const int r0 = blockIdx.x * 32;
    for (int i = t; i < 64 * OD; i += 256) {
        ws2[i / OD][i % OD] = W2[i];
    }
    for (int i = t; i < 32 * 64; i += 256) {
        int r = i >> 6, k = i & 63;
        hs[r][k] = h[(size_t)(r0 + r) * HD + k];
    }
    __syncthreads();
    for (int o = t; o < 32 * OD; o += 256) {
        int r = o / OD, c = o - r * OD;
        float s = 0.f;
        #pragma unroll
        for (int k = 0; k < HD; ++k)
            s = fmaf(hs[r][k], ws2[k][c], s);
        h2[(size_t)(r0 + r) * OD + c] = s;
    }
}

// ---------- self-loop + bias (layer 2, no relu) ----------
__global__ void k_sb2(float* __restrict__ out, const float* __restrict__ h2,
                      const float* __restrict__ dinv, const float* __restrict__ b2) {
    int idx = blockIdx.x * 256 + threadIdx.x;
    if (idx < NN * OD) {
        int n = idx / OD, c = idx - n * OD;
        float di = dinv[n];
        out[idx] += h2[idx] * di * di + b2[c];
    }
}

extern "C" void kernel_launch(void* const* d_in, const int* in_sizes, int n_in,
                              void* d_out, int out_size, void* d_ws, size_t ws_size,
                              hipStream_t stream) {
    const float* x  = (const float*)d_in[0];
    const float* W1 = (const float*)d_in[1];
    const float* b1 = (const float*)d_in[2];
    const float* W2 = (const float*)d_in[3];
    const float* b2 = (const float*)d_in[4];
    const void*  ei = d_in[5];
    float* out = (float*)d_out;

    char* ws = (char*)d_ws;
    int*   flags = (int*)ws;                                   // 1 KB reserved
    float* deg   = (float*)(ws + 1024);                        // NN floats (becomes dinv)
    float* norm  = (float*)(ws + 1024 + 401408);               // NE floats (6.4 MB)
    float* h1    = (float*)(ws + 1024 + 401408 + 6400000);     // NN*64 (25.6 MB)
    float* h1agg = (float*)(ws + 1024 + 401408 + 6400000 + 25600000); // NN*64
    float* h2    = h1;  // alias: h1 is dead after k_sb1relu

    k_detect<<<1, 64, 0, stream>>>((const unsigned*)ei, flags);
    k_initdeg<<<(NN + 255) / 256, 256, 0, stream>>>(deg);
    k_count<<<(NE + 255) / 256, 256, 0, stream>>>(ei, flags, deg);
    k_dinv<<<(NN + 255) / 256, 256, 0, stream>>>(deg);
    k_norm<<<(NE + 255) / 256, 256, 0, stream>>>(ei, flags, deg, norm);

    k_gemm1<<<(NN + 63) / 64, 256, 0, stream>>>(x, W1, h1);

    hipMemsetAsync(h1agg, 0, (size_t)NN * HD * 4, stream);
    k_agg64<<<(int)(((long long)NE * HD + 255) / 256), 256, 0, stream>>>(ei, flags, norm, h1, h1agg);
    k_sb1relu<<<(NN * HD + 255) / 256, 256, 0, stream>>>(h1agg, h1, deg, b1);

    k_gemm2<<<NN / 32, 256, 0, stream>>>(h1agg, W2, h2);

    hipMemsetAsync(out, 0, (size_t)NN * OD * 4, stream);
    k_agg40<<<(int)(((long long)NE * OD + 255) / 256), 256, 0, stream>>>(ei, flags, norm, h2, out);
    k_sb2<<<(NN * OD + 255) / 256, 256, 0, stream>>>(out, h2, deg, b2);
}

// Round 2
// 567.425 us; speedup vs baseline: 1.9056x; 1.9056x over previous
//
#include <hip/hip_runtime.h>
#include <cstdint>
#include <cstddef>

#define NN 100000
#define NE 1600000
#define IND 500
#define HD 64
#define OD 40
#define NBLK ((NN + 255) / 256)   // 391 scan blocks

// ---------- edge loading (int32 vs int64 auto-detect) ----------
static __device__ __forceinline__ int get_edge(const void* ei, int is64, size_t pos) {
    return is64 ? (int)((const long long*)ei)[pos] : ((const int*)ei)[pos];
}

__global__ void k_detect(const unsigned* ei32, int* flags) {
    if (threadIdx.x == 0 && blockIdx.x == 0) {
        int is64 = 1;
        #pragma unroll
        for (int i = 1; i < 16; i += 2)
            if (ei32[i] != 0u) is64 = 0;
        flags[0] = is64;
    }
}

// ---------- degree histogram ----------
__global__ void k_count(const void* ei, const int* __restrict__ flags, int* cnt) {
    int e = blockIdx.x * 256 + threadIdx.x;
    if (e < NE) {
        int d = get_edge(ei, flags[0], (size_t)NE + e);
        atomicAdd(&cnt[d], 1);
    }
}

__global__ void k_dinv(const int* __restrict__ cnt, float* __restrict__ dinv) {
    int i = blockIdx.x * 256 + threadIdx.x;
    if (i < NN) dinv[i] = rsqrtf((float)cnt[i] + 1.0f);  // +1 = self loop
}

// ---------- exclusive scan (3 kernels) ----------
__global__ __launch_bounds__(256) void k_scan_block(const int* __restrict__ cnt,
                                                    int* __restrict__ rowptr,
                                                    int* __restrict__ bsum) {
    int t = threadIdx.x;
    int i = blockIdx.x * 256 + t;
    int v = (i < NN) ? cnt[i] : 0;
    int inc = v;
    #pragma unroll
    for (int off = 1; off < 64; off <<= 1) {
        int u = __shfl_up(inc, off);
        if ((t & 63) >= off) inc += u;
    }
    __shared__ int wsum[4];
    if ((t & 63) == 63) wsum[t >> 6] = inc;
    __syncthreads();
    if (t == 0) {
        int a = 0;
        #pragma unroll
        for (int w = 0; w < 4; ++w) { int b = wsum[w]; wsum[w] = a; a += b; }
        bsum[blockIdx.x] = a;
    }
    __syncthreads();
    if (i < NN) rowptr[i] = inc - v + wsum[t >> 6];
}

__global__ __launch_bounds__(512) void k_scan_bsum(int* bsum) {
    int t = threadIdx.x;
    int v = (t < NBLK) ? bsum[t] : 0;
    int inc = v;
    #pragma unroll
    for (int off = 1; off < 64; off <<= 1) {
        int u = __shfl_up(inc, off);
        if ((t & 63) >= off) inc += u;
    }
    __shared__ int wsum[8];
    if ((t & 63) == 63) wsum[t >> 6] = inc;
    __syncthreads();
    if (t == 0) {
        int a = 0;
        #pragma unroll
        for (int w = 0; w < 8; ++w) { int b = wsum[w]; wsum[w] = a; a += b; }
    }
    __syncthreads();
    if (t < NBLK) bsum[t] = inc - v + wsum[t >> 6];
}

__global__ void k_scan_add(int* rowptr, const int* __restrict__ bsum) {
    int i = blockIdx.x * 256 + threadIdx.x;
    if (i < NN) rowptr[i] += bsum[i >> 8];
    if (i == 0) rowptr[NN] = NE;
}

// ---------- counting-sort edges by dst ----------
__global__ void k_scatter(const void* ei, const int* __restrict__ flags,
                          const int* __restrict__ rowptr, int* cursor,
                          int* __restrict__ srcs) {
    int e = blockIdx.x * 256 + threadIdx.x;
    if (e < NE) {
        int is64 = flags[0];
        int s = get_edge(ei, is64, (size_t)e);
        int d = get_edge(ei, is64, (size_t)NE + e);
        int pos = rowptr[d] + atomicAdd(&cursor[d], 1);
        srcs[pos] = s;
    }
}

// ---------- GEMM1: h1[100000x64] = x[100000x500] @ W1[500x64] ----------
#define KC 50
__global__ __launch_bounds__(256) void k_gemm1(const float* __restrict__ x,
                                               const float* __restrict__ W,
                                               float* __restrict__ h) {
    __shared__ float xs[KC][68];
    __shared__ float wsh[KC][64];
    const int t = threadIdx.x;
    const int row0 = blockIdx.x * 64;
    const int tx = t & 15;
    const int ty = t >> 4;
    float acc[4][4];
    #pragma unroll
    for (int i = 0; i < 4; ++i)
        #pragma unroll
        for (int j = 0; j < 4; ++j) acc[i][j] = 0.f;

    for (int kk = 0; kk < IND; kk += KC) {
        for (int i = t; i < 64 * KC; i += 256) {
            int r = i / KC, k = i - r * KC;
            int grow = row0 + r;
            xs[k][r] = (grow < NN) ? x[(size_t)grow * IND + kk + k] : 0.f;
        }
        for (int i = t; i < KC * 64; i += 256) {
            int k = i >> 6, c = i & 63;
            wsh[k][c] = W[(size_t)(kk + k) * HD + c];
        }
        __syncthreads();
        #pragma unroll 10
        for (int k = 0; k < KC; ++k) {
            float4 xv = *(const float4*)&xs[k][ty * 4];
            float4 wv = *(const float4*)&wsh[k][tx * 4];
            float xa[4] = {xv.x, xv.y, xv.z, xv.w};
            float wa[4] = {wv.x, wv.y, wv.z, wv.w};
            #pragma unroll
            for (int i = 0; i < 4; ++i)
                #pragma unroll
                for (int j = 0; j < 4; ++j)
                    acc[i][j] = fmaf(xa[i], wa[j], acc[i][j]);
        }
        __syncthreads();
    }
    #pragma unroll
    for (int i = 0; i < 4; ++i) {
        int grow = row0 + ty * 4 + i;
        if (grow < NN) {
            float4 v = make_float4(acc[i][0], acc[i][1], acc[i][2], acc[i][3]);
            *(float4*)&h[(size_t)grow * HD + tx * 4] = v;
        }
    }
}

// ---------- CSR aggregation: wave per node, lane = channel ----------
template<bool RELU_BIAS>
__global__ __launch_bounds__(256) void k_agg(const int* __restrict__ rowptr,
                                             const int* __restrict__ srcs,
                                             const float* __restrict__ dinv,
                                             const float* __restrict__ hin,
                                             const float* __restrict__ bias,
                                             float* __restrict__ hout) {
    int wid = (blockIdx.x * 256 + threadIdx.x) >> 6;
    int lane = threadIdx.x & 63;
    if (wid >= NN) return;
    float dn = dinv[wid];
    float acc = hin[(size_t)wid * HD + lane] * dn * dn;   // self loop
    if (RELU_BIAS) acc += bias[lane];
    int e = rowptr[wid];
    const int end = rowptr[wid + 1];
    for (; e + 4 <= end; e += 4) {
        int s0 = srcs[e], s1 = srcs[e + 1], s2 = srcs[e + 2], s3 = srcs[e + 3];
        float w0 = dinv[s0] * dn, w1 = dinv[s1] * dn;
        float w2 = dinv[s2] * dn, w3 = dinv[s3] * dn;
        float v0 = hin[(size_t)s0 * HD + lane];
        float v1 = hin[(size_t)s1 * HD + lane];
        float v2 = hin[(size_t)s2 * HD + lane];
        float v3 = hin[(size_t)s3 * HD + lane];
        acc = fmaf(v0, w0, acc);
        acc = fmaf(v1, w1, acc);
        acc = fmaf(v2, w2, acc);
        acc = fmaf(v3, w3, acc);
    }
    for (; e < end; ++e) {
        int s = srcs[e];
        acc = fmaf(hin[(size_t)s * HD + lane], dinv[s] * dn, acc);
    }
    if (RELU_BIAS) acc = fmaxf(acc, 0.f);
    hout[(size_t)wid * HD + lane] = acc;
}

// ---------- GEMM2 + bias: out = agg2 @ W2 + b2 ----------
__global__ __launch_bounds__(256) void k_gemm2(const float* __restrict__ h,
                                               const float* __restrict__ W2,
                                               const float* __restrict__ b2,
                                               float* __restrict__ out) {
    __shared__ float hs[32][65];
    __shared__ float ws2[64][40];
    const int t = threadIdx.x;
    const int r0 = blockIdx.x * 32;
    for (int i = t; i < 64 * OD; i += 256)
        ws2[i / OD][i % OD] = W2[i];
    for (int i = t; i < 32 * 64; i += 256) {
        int r = i >> 6, k = i & 63;
        hs[r][k] = h[(size_t)(r0 + r) * HD + k];
    }
    __syncthreads();
    for (int o = t; o < 32 * OD; o += 256) {
        int r = o / OD, c = o - r * OD;
        float s = 0.f;
        #pragma unroll
        for (int k = 0; k < HD; ++k)
            s = fmaf(hs[r][k], ws2[k][c], s);
        out[(size_t)(r0 + r) * OD + c] = s + b2[c];
    }
}

extern "C" void kernel_launch(void* const* d_in, const int* in_sizes, int n_in,
                              void* d_out, int out_size, void* d_ws, size_t ws_size,
                              hipStream_t stream) {
    const float* x  = (const float*)d_in[0];
    const float* W1 = (const float*)d_in[1];
    const float* b1 = (const float*)d_in[2];
    const float* W2 = (const float*)d_in[3];
    const float* b2 = (const float*)d_in[4];
    const void*  ei = d_in[5];
    float* out = (float*)d_out;

    // --- scratch carved out of d_out (16 MB); all dead before k_gemm2 writes out ---
    char* ob = (char*)d_out;
    int*   rowptr = (int*)ob;                    // (NN+1)*4 = 400,004 B
    int*   cursor = (int*)(ob + 400896);         // 400,000 B (histogram, then sort cursor)
    int*   bsum   = (int*)(ob + 801280);         // 1,564 B
    int*   srcs   = (int*)(ob + 803328);         // 6,400,000 B  (end 7,203,328)
    float* dinv   = (float*)(ob + 7203840);      // 400,000 B    (end 7,603,840 < 16 MB)

    // --- ws: feature matrices ---
    char* ws = (char*)d_ws;
    int*   flags = (int*)ws;                     // 1 KB
    float* h1    = (float*)(ws + 1024);          // 25.6 MB
    float* hrelu = (float*)(ws + 1024 + 25600000); // 25.6 MB (end 51.2 MB)
    float* agg2  = h1;                           // alias: h1 dead after layer-1 agg

    k_detect<<<1, 64, 0, stream>>>((const unsigned*)ei, flags);

    // CSR build
    hipMemsetAsync(cursor, 0, (size_t)NN * 4, stream);
    k_count<<<(NE + 255) / 256, 256, 0, stream>>>(ei, flags, cursor);
    k_dinv<<<(NN + 255) / 256, 256, 0, stream>>>(cursor, dinv);
    k_scan_block<<<NBLK, 256, 0, stream>>>(cursor, rowptr, bsum);
    k_scan_bsum<<<1, 512, 0, stream>>>(bsum);
    k_scan_add<<<NBLK, 256, 0, stream>>>(rowptr, bsum);
    hipMemsetAsync(cursor, 0, (size_t)NN * 4, stream);
    k_scatter<<<(NE + 255) / 256, 256, 0, stream>>>(ei, flags, rowptr, cursor, srcs);

    // layer 1
    k_gemm1<<<(NN + 63) / 64, 256, 0, stream>>>(x, W1, h1);
    k_agg<true><<<(NN * 64) / 256, 256, 0, stream>>>(rowptr, srcs, dinv, h1, b1, hrelu);

    // layer 2: aggregate first (commutes with the linear map), then GEMM+bias
    k_agg<false><<<(NN * 64) / 256, 256, 0, stream>>>(rowptr, srcs, dinv, hrelu, (const float*)nullptr, agg2);
    k_gemm2<<<NN / 32, 256, 0, stream>>>(agg2, W2, b2, out);
}

// Round 3
// 440.100 us; speedup vs baseline: 2.4569x; 1.2893x over previous
//
#include <hip/hip_runtime.h>
#include <cstdint>
#include <cstddef>

#define NN 100000
#define NE 1600000
#define IND 500
#define HD 64
#define OD 40
#define NBLK ((NN + 255) / 256)   // 391 scan blocks
#define KSTEPS 16                 // ceil(500/32)

typedef __attribute__((ext_vector_type(8))) short short8v;
typedef __attribute__((ext_vector_type(8))) __bf16 bf16x8;
typedef __attribute__((ext_vector_type(4))) float float4v;

// MFMA builtin signature differs across toolchains (short8 vs bf16x8).
// SFINAE: prefer direct call; fall back to same-size vector bitcast.
template <class V>
static __device__ __forceinline__ auto mfma_bf16_(V a, V b, float4v c, int)
    -> decltype(__builtin_amdgcn_mfma_f32_16x16x32_bf16(a, b, c, 0, 0, 0)) {
    return __builtin_amdgcn_mfma_f32_16x16x32_bf16(a, b, c, 0, 0, 0);
}
template <class V>
static __device__ __forceinline__ float4v mfma_bf16_(V a, V b, float4v c, long) {
    return __builtin_amdgcn_mfma_f32_16x16x32_bf16((bf16x8)a, (bf16x8)b, c, 0, 0, 0);
}
static __device__ __forceinline__ float4v mfma16(short8v a, short8v b, float4v c) {
    return mfma_bf16_(a, b, c, 0);
}

// ---------- edge loading (int32 vs int64 auto-detect) ----------
static __device__ __forceinline__ int get_edge(const void* ei, int is64, size_t pos) {
    return is64 ? (int)((const long long*)ei)[pos] : ((const int*)ei)[pos];
}

__global__ void k_detect(const unsigned* ei32, int* flags) {
    if (threadIdx.x == 0 && blockIdx.x == 0) {
        int is64 = 1;
        #pragma unroll
        for (int i = 1; i < 16; i += 2)
            if (ei32[i] != 0u) is64 = 0;
        flags[0] = is64;
    }
}

// ---------- degree histogram ----------
__global__ void k_count(const void* ei, const int* __restrict__ flags, int* cnt) {
    int e = blockIdx.x * 256 + threadIdx.x;
    if (e < NE) {
        int d = get_edge(ei, flags[0], (size_t)NE + e);
        atomicAdd(&cnt[d], 1);
    }
}

__global__ void k_dinv(const int* __restrict__ cnt, float* __restrict__ dinv) {
    int i = blockIdx.x * 256 + threadIdx.x;
    if (i < NN) dinv[i] = rsqrtf((float)cnt[i] + 1.0f);  // +1 = self loop
}

// ---------- exclusive scan (3 kernels) ----------
__global__ __launch_bounds__(256) void k_scan_block(const int* __restrict__ cnt,
                                                    int* __restrict__ rowptr,
                                                    int* __restrict__ bsum) {
    int t = threadIdx.x;
    int i = blockIdx.x * 256 + t;
    int v = (i < NN) ? cnt[i] : 0;
    int inc = v;
    #pragma unroll
    for (int off = 1; off < 64; off <<= 1) {
        int u = __shfl_up(inc, off);
        if ((t & 63) >= off) inc += u;
    }
    __shared__ int wsum[4];
    if ((t & 63) == 63) wsum[t >> 6] = inc;
    __syncthreads();
    if (t == 0) {
        int a = 0;
        #pragma unroll
        for (int w = 0; w < 4; ++w) { int b = wsum[w]; wsum[w] = a; a += b; }
        bsum[blockIdx.x] = a;
    }
    __syncthreads();
    if (i < NN) rowptr[i] = inc - v + wsum[t >> 6];
}

__global__ __launch_bounds__(512) void k_scan_bsum(int* bsum) {
    int t = threadIdx.x;
    int v = (t < NBLK) ? bsum[t] : 0;
    int inc = v;
    #pragma unroll
    for (int off = 1; off < 64; off <<= 1) {
        int u = __shfl_up(inc, off);
        if ((t & 63) >= off) inc += u;
    }
    __shared__ int wsum[8];
    if ((t & 63) == 63) wsum[t >> 6] = inc;
    __syncthreads();
    if (t == 0) {
        int a = 0;
        #pragma unroll
        for (int w = 0; w < 8; ++w) { int b = wsum[w]; wsum[w] = a; a += b; }
    }
    __syncthreads();
    if (t < NBLK) bsum[t] = inc - v + wsum[t >> 6];
}

__global__ void k_scan_add(int* rowptr, const int* __restrict__ bsum) {
    int i = blockIdx.x * 256 + threadIdx.x;
    if (i < NN) rowptr[i] += bsum[i >> 8];
    if (i == 0) rowptr[NN] = NE;
}

// ---------- counting-sort edges by dst ----------
__global__ void k_scatter(const void* ei, const int* __restrict__ flags,
                          const int* __restrict__ rowptr, int* cursor,
                          int* __restrict__ srcs) {
    int e = blockIdx.x * 256 + threadIdx.x;
    if (e < NE) {
        int is64 = flags[0];
        int s = get_edge(ei, is64, (size_t)e);
        int d = get_edge(ei, is64, (size_t)NE + e);
        int pos = rowptr[d] + atomicAdd(&cursor[d], 1);
        srcs[pos] = s;
    }
}

// ---------- W1 prep: pack into MFMA fragment order, split hi/lo bf16 ----------
// layout: frag index t = (s*4 + f)*64 + lane; 8 bf16 per frag (j = k within group)
// lane: n = f*16 + (lane&15), k = s*32 + 8*(lane>>4) + j
__global__ void k_prepw(const float* __restrict__ W, unsigned short* __restrict__ wh,
                        unsigned short* __restrict__ wl) {
    int t = blockIdx.x * 256 + threadIdx.x;
    if (t >= KSTEPS * 4 * 64) return;
    int l = t & 63;
    int f = (t >> 6) & 3;
    int s = t >> 8;
    int n = f * 16 + (l & 15);
    int kbase = s * 32 + 8 * (l >> 4);
    unsigned short* ph = wh + (size_t)t * 8;
    unsigned short* pl = wl + (size_t)t * 8;
    #pragma unroll
    for (int j = 0; j < 8; ++j) {
        int k = kbase + j;
        float v = (k < IND) ? W[(size_t)k * HD + n] : 0.f;
        unsigned u = __float_as_uint(v);
        unsigned short hb = (unsigned short)(u >> 16);              // trunc hi
        float r = v - __uint_as_float(u & 0xffff0000u);
        unsigned ur = __float_as_uint(r);
        unsigned short lb = (unsigned short)((ur + 0x7fffu + ((ur >> 16) & 1u)) >> 16); // RNE lo
        ph[j] = hb;
        pl[j] = lb;
    }
}

// ---------- GEMM1 (MFMA): h1[100000x64] = x[100000x500] @ W1[500x64] ----------
// block = 256 threads = 4 waves; each wave: 32 rows x 64 cols; no LDS.
__global__ __launch_bounds__(256) void k_gemm1m(const float* __restrict__ x,
                                                const short8v* __restrict__ wh,
                                                const short8v* __restrict__ wl,
                                                float* __restrict__ h) {
    const int lane = threadIdx.x & 63;
    const int wave = threadIdx.x >> 6;
    const int row0 = (blockIdx.x * 4 + wave) * 32;
    if (row0 >= NN) return;
    const int rA = lane & 15;   // row within 16-tile (A) / col within tile (B, C)
    const int cg = lane >> 4;   // k-group

    float4v acc[2][4];
    const float4v zero4 = {0.f, 0.f, 0.f, 0.f};
    #pragma unroll
    for (int mi = 0; mi < 2; ++mi)
        #pragma unroll
        for (int f = 0; f < 4; ++f) acc[mi][f] = zero4;

    const float* xp0 = x + (size_t)(row0 + rA) * IND;
    const float* xp1 = xp0 + (size_t)16 * IND;

    #pragma unroll 2
    for (int s = 0; s < KSTEPS; ++s) {
        const int k0 = s * 32 + cg * 8;
        short8v ah[2], al[2];
        #pragma unroll
        for (int mi = 0; mi < 2; ++mi) {
            const float* xp = (mi ? xp1 : xp0) + k0;
            float xv[8];
            if (s < KSTEPS - 1) {
                float4 u0 = *(const float4*)xp;
                float4 u1 = *(const float4*)(xp + 4);
                xv[0] = u0.x; xv[1] = u0.y; xv[2] = u0.z; xv[3] = u0.w;
                xv[4] = u1.x; xv[5] = u1.y; xv[6] = u1.z; xv[7] = u1.w;
            } else {
                #pragma unroll
                for (int j = 0; j < 8; ++j)
                    xv[j] = (k0 + j < IND) ? xp[j] : 0.f;
            }
            #pragma unroll
            for (int j = 0; j < 8; ++j) {
                unsigned u = __float_as_uint(xv[j]);
                ah[mi][j] = (short)(u >> 16);                      // trunc hi
                float r = xv[j] - __uint_as_float(u & 0xffff0000u);
                unsigned ur = __float_as_uint(r);
                al[mi][j] = (short)((ur + 0x7fffu + ((ur >> 16) & 1u)) >> 16); // RNE lo
            }
        }
        const short8v* bhp = wh + (size_t)(s * 4) * 64 + lane;
        const short8v* blp = wl + (size_t)(s * 4) * 64 + lane;
        #pragma unroll
        for (int f = 0; f < 4; ++f) {
            short8v vh = bhp[(size_t)f * 64];
            short8v vl = blp[(size_t)f * 64];
            #pragma unroll
            for (int mi = 0; mi < 2; ++mi) {
                acc[mi][f] = mfma16(al[mi], vh, acc[mi][f]);
                acc[mi][f] = mfma16(ah[mi], vl, acc[mi][f]);
                acc[mi][f] = mfma16(ah[mi], vh, acc[mi][f]);
            }
        }
    }

    // C/D layout (m89-verified): col = lane&15, row = (lane>>4)*4 + reg
    #pragma unroll
    for (int mi = 0; mi < 2; ++mi)
        #pragma unroll
        for (int f = 0; f < 4; ++f)
            #pragma unroll
            for (int j = 0; j < 4; ++j) {
                int row = row0 + mi * 16 + cg * 4 + j;
                h[(size_t)row * HD + f * 16 + rA] = acc[mi][f][j];
            }
}

// ---------- CSR aggregation: wave per node, lane = channel ----------
template<bool RELU_BIAS>
__global__ __launch_bounds__(256) void k_agg(const int* __restrict__ rowptr,
                                             const int* __restrict__ srcs,
                                             const float* __restrict__ dinv,
                                             const float* __restrict__ hin,
                                             const float* __restrict__ bias,
                                             float* __restrict__ hout) {
    int wid = (blockIdx.x * 256 + threadIdx.x) >> 6;
    int lane = threadIdx.x & 63;
    if (wid >= NN) return;
    float dn = dinv[wid];
    float acc = hin[(size_t)wid * HD + lane] * dn * dn;   // self loop
    if (RELU_BIAS) acc += bias[lane];
    int e = rowptr[wid];
    const int end = rowptr[wid + 1];
    for (; e + 4 <= end; e += 4) {
        int s0 = srcs[e], s1 = srcs[e + 1], s2 = srcs[e + 2], s3 = srcs[e + 3];
        float w0 = dinv[s0] * dn, w1 = dinv[s1] * dn;
        float w2 = dinv[s2] * dn, w3 = dinv[s3] * dn;
        float v0 = hin[(size_t)s0 * HD + lane];
        float v1 = hin[(size_t)s1 * HD + lane];
        float v2 = hin[(size_t)s2 * HD + lane];
        float v3 = hin[(size_t)s3 * HD + lane];
        acc = fmaf(v0, w0, acc);
        acc = fmaf(v1, w1, acc);
        acc = fmaf(v2, w2, acc);
        acc = fmaf(v3, w3, acc);
    }
    for (; e < end; ++e) {
        int s = srcs[e];
        acc = fmaf(hin[(size_t)s * HD + lane], dinv[s] * dn, acc);
    }
    if (RELU_BIAS) acc = fmaxf(acc, 0.f);
    hout[(size_t)wid * HD + lane] = acc;
}

// ---------- GEMM2 + bias: out = agg2 @ W2 + b2 ----------
__global__ __launch_bounds__(256) void k_gemm2(const float* __restrict__ h,
                                               const float* __restrict__ W2,
                                               const float* __restrict__ b2,
                                               float* __restrict__ out) {
    __shared__ float hs[32][65];
    __shared__ float ws2[64][40];
    const int t = threadIdx.x;
    const int r0 = blockIdx.x * 32;
    for (int i = t; i < 64 * OD; i += 256)
        ws2[i / OD][i % OD] = W2[i];
    for (int i = t; i < 32 * 64; i += 256) {
        int r = i >> 6, k = i & 63;
        hs[r][k] = h[(size_t)(r0 + r) * HD + k];
    }
    __syncthreads();
    for (int o = t; o < 32 * OD; o += 256) {
        int r = o / OD, c = o - r * OD;
        float s = 0.f;
        #pragma unroll
        for (int k = 0; k < HD; ++k)
            s = fmaf(hs[r][k], ws2[k][c], s);
        out[(size_t)(r0 + r) * OD + c] = s + b2[c];
    }
}

extern "C" void kernel_launch(void* const* d_in, const int* in_sizes, int n_in,
                              void* d_out, int out_size, void* d_ws, size_t ws_size,
                              hipStream_t stream) {
    const float* x  = (const float*)d_in[0];
    const float* W1 = (const float*)d_in[1];
    const float* b1 = (const float*)d_in[2];
    const float* W2 = (const float*)d_in[3];
    const float* b2 = (const float*)d_in[4];
    const void*  ei = d_in[5];
    float* out = (float*)d_out;

    // --- scratch carved out of d_out (16 MB); all dead before k_gemm2 writes out ---
    char* ob = (char*)d_out;
    int*   rowptr = (int*)ob;                         // 400,004 B
    int*   cursor = (int*)(ob + 400896);              // 400,000 B
    int*   bsum   = (int*)(ob + 801280);              // 1,564 B
    int*   srcs   = (int*)(ob + 803328);              // 6,400,000 B (end 7,203,328)
    float* dinv   = (float*)(ob + 7203840);           // 400,000 B (end 7,603,840)
    unsigned short* wh = (unsigned short*)(ob + 8000000); // 65,536 B
    unsigned short* wl = (unsigned short*)(ob + 8065536); // 65,536 B (end 8,131,072 < 16 MB)

    // --- ws: feature matrices ---
    char* ws = (char*)d_ws;
    int*   flags = (int*)ws;                          // 1 KB
    float* h1    = (float*)(ws + 1024);               // 25.6 MB
    float* hrelu = (float*)(ws + 1024 + 25600000);    // 25.6 MB
    float* agg2  = h1;                                // alias: h1 dead after layer-1 agg

    k_detect<<<1, 64, 0, stream>>>((const unsigned*)ei, flags);
    k_prepw<<<(KSTEPS * 4 * 64 + 255) / 256, 256, 0, stream>>>(W1, wh, wl);

    // CSR build
    hipMemsetAsync(cursor, 0, (size_t)NN * 4, stream);
    k_count<<<(NE + 255) / 256, 256, 0, stream>>>(ei, flags, cursor);
    k_dinv<<<(NN + 255) / 256, 256, 0, stream>>>(cursor, dinv);
    k_scan_block<<<NBLK, 256, 0, stream>>>(cursor, rowptr, bsum);
    k_scan_bsum<<<1, 512, 0, stream>>>(bsum);
    k_scan_add<<<NBLK, 256, 0, stream>>>(rowptr, bsum);
    hipMemsetAsync(cursor, 0, (size_t)NN * 4, stream);
    k_scatter<<<(NE + 255) / 256, 256, 0, stream>>>(ei, flags, rowptr, cursor, srcs);

    // layer 1: MFMA GEMM (split-bf16), then CSR aggregation
    k_gemm1m<<<(NN / 32 + 3) / 4, 256, 0, stream>>>(x, (const short8v*)wh, (const short8v*)wl, h1);
    k_agg<true><<<(NN * 64) / 256, 256, 0, stream>>>(rowptr, srcs, dinv, h1, b1, hrelu);

    // layer 2: aggregate first (commutes with linear map), then GEMM+bias
    k_agg<false><<<(NN * 64) / 256, 256, 0, stream>>>(rowptr, srcs, dinv, hrelu, (const float*)nullptr, agg2);
    k_gemm2<<<NN / 32, 256, 0, stream>>>(agg2, W2, b2, out);
}

// Round 4
// 348.026 us; speedup vs baseline: 3.1069x; 1.2646x over previous
//
#include <hip/hip_runtime.h>
#include <cstdint>
#include <cstddef>

#define NN 100000
#define NE 1600000
#define IND 500
#define HD 64
#define OD 40
#define NBLK ((NN + 255) / 256)   // 391 scan blocks
#define KSTEPS 16                 // ceil(500/32)

typedef __attribute__((ext_vector_type(8))) short short8v;
typedef __attribute__((ext_vector_type(8))) __bf16 bf16x8;
typedef __attribute__((ext_vector_type(4))) float float4v;

// MFMA builtin signature differs across toolchains (short8 vs bf16x8).
template <class V>
static __device__ __forceinline__ auto mfma_bf16_(V a, V b, float4v c, int)
    -> decltype(__builtin_amdgcn_mfma_f32_16x16x32_bf16(a, b, c, 0, 0, 0)) {
    return __builtin_amdgcn_mfma_f32_16x16x32_bf16(a, b, c, 0, 0, 0);
}
template <class V>
static __device__ __forceinline__ float4v mfma_bf16_(V a, V b, float4v c, long) {
    return __builtin_amdgcn_mfma_f32_16x16x32_bf16((bf16x8)a, (bf16x8)b, c, 0, 0, 0);
}
static __device__ __forceinline__ float4v mfma16(short8v a, short8v b, float4v c) {
    return mfma_bf16_(a, b, c, 0);
}

static __device__ __forceinline__ float bf2f(unsigned short v) {
    return __uint_as_float((unsigned)v << 16);
}
static __device__ __forceinline__ unsigned short f2bf(float v) {
    unsigned u = __float_as_uint(v);
    return (unsigned short)((u + 0x7fffu + ((u >> 16) & 1u)) >> 16);
}

// ---------- edge loading (int32 vs int64 auto-detect) ----------
__global__ void k_detect(const unsigned* ei32, int* flags) {
    if (threadIdx.x == 0 && blockIdx.x == 0) {
        int is64 = 1;
        #pragma unroll
        for (int i = 1; i < 16; i += 2)
            if (ei32[i] != 0u) is64 = 0;
        flags[0] = is64;
    }
}

// load 4 consecutive edge entries starting at element index base (base % 4 == 0)
static __device__ __forceinline__ void load4e(const void* ei, int is64, size_t base, int v[4]) {
    if (is64) {
        int4 a = ((const int4*)ei)[base >> 1];
        int4 b = ((const int4*)ei)[(base >> 1) + 1];
        v[0] = a.x; v[1] = a.z; v[2] = b.x; v[3] = b.z;
    } else {
        int4 a = *(const int4*)((const int*)ei + base);
        v[0] = a.x; v[1] = a.y; v[2] = a.z; v[3] = a.w;
    }
}

// ---------- degree histogram + per-edge rank (atomic return value) ----------
__global__ void k_count(const void* ei, const int* __restrict__ flags, int* cnt,
                        int* __restrict__ rank) {
    int e0 = (blockIdx.x * 256 + threadIdx.x) * 4;
    if (e0 >= NE) return;
    int d[4];
    load4e(ei, flags[0], (size_t)NE + e0, d);
    int4 r;
    r.x = atomicAdd(&cnt[d[0]], 1);
    r.y = atomicAdd(&cnt[d[1]], 1);
    r.z = atomicAdd(&cnt[d[2]], 1);
    r.w = atomicAdd(&cnt[d[3]], 1);
    *(int4*)(rank + e0) = r;
}

__global__ void k_dinv(const int* __restrict__ cnt, float* __restrict__ dinv) {
    int i = blockIdx.x * 256 + threadIdx.x;
    if (i < NN) dinv[i] = rsqrtf((float)cnt[i] + 1.0f);  // +1 = self loop
}

// ---------- exclusive scan (3 kernels) ----------
__global__ __launch_bounds__(256) void k_scan_block(const int* __restrict__ cnt,
                                                    int* __restrict__ rowptr,
                                                    int* __restrict__ bsum) {
    int t = threadIdx.x;
    int i = blockIdx.x * 256 + t;
    int v = (i < NN) ? cnt[i] : 0;
    int inc = v;
    #pragma unroll
    for (int off = 1; off < 64; off <<= 1) {
        int u = __shfl_up(inc, off);
        if ((t & 63) >= off) inc += u;
    }
    __shared__ int wsum[4];
    if ((t & 63) == 63) wsum[t >> 6] = inc;
    __syncthreads();
    if (t == 0) {
        int a = 0;
        #pragma unroll
        for (int w = 0; w < 4; ++w) { int b = wsum[w]; wsum[w] = a; a += b; }
        bsum[blockIdx.x] = a;
    }
    __syncthreads();
    if (i < NN) rowptr[i] = inc - v + wsum[t >> 6];
}

__global__ __launch_bounds__(512) void k_scan_bsum(int* bsum) {
    int t = threadIdx.x;
    int v = (t < NBLK) ? bsum[t] : 0;
    int inc = v;
    #pragma unroll
    for (int off = 1; off < 64; off <<= 1) {
        int u = __shfl_up(inc, off);
        if ((t & 63) >= off) inc += u;
    }
    __shared__ int wsum[8];
    if ((t & 63) == 63) wsum[t >> 6] = inc;
    __syncthreads();
    if (t == 0) {
        int a = 0;
        #pragma unroll
        for (int w = 0; w < 8; ++w) { int b = wsum[w]; wsum[w] = a; a += b; }
    }
    __syncthreads();
    if (t < NBLK) bsum[t] = inc - v + wsum[t >> 6];
}

__global__ void k_scan_add(int* rowptr, const int* __restrict__ bsum) {
    int i = blockIdx.x * 256 + threadIdx.x;
    if (i < NN) rowptr[i] += bsum[i >> 8];
    if (i == 0) rowptr[NN] = NE;
}

// ---------- counting-sort scatter (no atomics: pos = rowptr[d] + rank[e]) ----------
__global__ void k_scatter(const void* ei, const int* __restrict__ flags,
                          const int* __restrict__ rowptr, const int* __restrict__ rank,
                          int* __restrict__ srcs) {
    int e0 = (blockIdx.x * 256 + threadIdx.x) * 4;
    if (e0 >= NE) return;
    int is64 = flags[0];
    int s[4], d[4];
    load4e(ei, is64, (size_t)e0, s);
    load4e(ei, is64, (size_t)NE + e0, d);
    int4 r = *(const int4*)(rank + e0);
    int p0 = rowptr[d[0]] + r.x;
    int p1 = rowptr[d[1]] + r.y;
    int p2 = rowptr[d[2]] + r.z;
    int p3 = rowptr[d[3]] + r.w;
    srcs[p0] = s[0];
    srcs[p1] = s[1];
    srcs[p2] = s[2];
    srcs[p3] = s[3];
}

// ---------- W1 prep: pack into MFMA fragment order, split hi/lo bf16 ----------
__global__ void k_prepw(const float* __restrict__ W, unsigned short* __restrict__ wh,
                        unsigned short* __restrict__ wl) {
    int t = blockIdx.x * 256 + threadIdx.x;
    if (t >= KSTEPS * 4 * 64) return;
    int l = t & 63;
    int f = (t >> 6) & 3;
    int s = t >> 8;
    int n = f * 16 + (l & 15);
    int kbase = s * 32 + 8 * (l >> 4);
    unsigned short* ph = wh + (size_t)t * 8;
    unsigned short* pl = wl + (size_t)t * 8;
    #pragma unroll
    for (int j = 0; j < 8; ++j) {
        int k = kbase + j;
        float v = (k < IND) ? W[(size_t)k * HD + n] : 0.f;
        unsigned u = __float_as_uint(v);
        unsigned short hb = (unsigned short)(u >> 16);              // trunc hi
        float r = v - __uint_as_float(u & 0xffff0000u);
        ph[j] = hb;
        pl[j] = f2bf(r);
    }
}

// ---------- GEMM1 (MFMA, prefetched): hs[i] = bf16( dinv[i] * (x @ W1)[i] ) ----------
struct XF { float4 a, b; };
static __device__ __forceinline__ XF ldx(const float* p) {
    XF r; r.a = *(const float4*)p; r.b = *(const float4*)(p + 4); return r;
}
static __device__ __forceinline__ XF ldx_tail(const float* p, int k0) {
    float t[8];
    #pragma unroll
    for (int j = 0; j < 8; ++j) t[j] = (k0 + j < IND) ? p[j] : 0.f;
    XF r;
    r.a = make_float4(t[0], t[1], t[2], t[3]);
    r.b = make_float4(t[4], t[5], t[6], t[7]);
    return r;
}
static __device__ __forceinline__ void split8(const XF& u, short8v& hi, short8v& lo) {
    float t[8] = {u.a.x, u.a.y, u.a.z, u.a.w, u.b.x, u.b.y, u.b.z, u.b.w};
    #pragma unroll
    for (int j = 0; j < 8; ++j) {
        unsigned q = __float_as_uint(t[j]);
        hi[j] = (short)(q >> 16);
        float r = t[j] - __uint_as_float(q & 0xffff0000u);
        lo[j] = (short)f2bf(r);
    }
}

__global__ __launch_bounds__(256) void k_gemm1m(const float* __restrict__ x,
                                                const short8v* __restrict__ wh,
                                                const short8v* __restrict__ wl,
                                                const float* __restrict__ dinv,
                                                unsigned short* __restrict__ h) {
    const int lane = threadIdx.x & 63;
    const int wave = threadIdx.x >> 6;
    const int row0 = (blockIdx.x * 4 + wave) * 32;
    if (row0 >= NN) return;
    const int rA = lane & 15;
    const int cg = lane >> 4;
    const bool tailw = (row0 == NN - 32);   // wave containing row NN-1

    float4v acc[2][4];
    const float4v zero4 = {0.f, 0.f, 0.f, 0.f};
    #pragma unroll
    for (int mi = 0; mi < 2; ++mi)
        #pragma unroll
        for (int f = 0; f < 4; ++f) acc[mi][f] = zero4;

    const float* xq0 = x + (size_t)(row0 + rA) * IND + cg * 8;
    const float* xq1 = xq0 + (size_t)16 * IND;

    XF cur0 = ldx(xq0), cur1 = ldx(xq1);
    #pragma unroll
    for (int s = 0; s < KSTEPS; ++s) {
        XF nxt0, nxt1;
        if (s + 1 < KSTEPS) {
            const float* p0 = xq0 + (s + 1) * 32;
            const float* p1 = xq1 + (s + 1) * 32;
            if (s + 1 == KSTEPS - 1 && tailw) {
                int k0 = (KSTEPS - 1) * 32 + cg * 8;
                nxt0 = ldx_tail(p0, k0);
                nxt1 = ldx_tail(p1, k0);
            } else {
                nxt0 = ldx(p0);
                nxt1 = ldx(p1);
            }
        }
        short8v ah0, al0, ah1, al1;
        split8(cur0, ah0, al0);
        split8(cur1, ah1, al1);
        const short8v* bhp = wh + (size_t)s * 256 + lane;
        const short8v* blp = wl + (size_t)s * 256 + lane;
        #pragma unroll
        for (int f = 0; f < 4; ++f) {
            short8v vh = bhp[(size_t)f * 64];
            short8v vl = blp[(size_t)f * 64];
            acc[0][f] = mfma16(al0, vh, acc[0][f]);
            acc[0][f] = mfma16(ah0, vl, acc[0][f]);
            acc[0][f] = mfma16(ah0, vh, acc[0][f]);
            acc[1][f] = mfma16(al1, vh, acc[1][f]);
            acc[1][f] = mfma16(ah1, vl, acc[1][f]);
            acc[1][f] = mfma16(ah1, vh, acc[1][f]);
        }
        cur0 = nxt0;
        cur1 = nxt1;
    }

    // C/D layout (m89-verified): col = lane&15, row = (lane>>4)*4 + reg
    #pragma unroll
    for (int mi = 0; mi < 2; ++mi)
        #pragma unroll
        for (int j = 0; j < 4; ++j) {
            int row = row0 + mi * 16 + cg * 4 + j;
            float dv = dinv[row];
            #pragma unroll
            for (int f = 0; f < 4; ++f)
                h[(size_t)row * HD + f * 16 + rA] = f2bf(acc[mi][f][j] * dv);
        }
}

// ---------- CSR aggregation: out[d] = dn * sum(hs[s]) ; wave per node, lane = channel ----------
template<bool L1>
__global__ __launch_bounds__(256) void k_agg(const int* __restrict__ rowptr,
                                             const int* __restrict__ srcs,
                                             const float* __restrict__ dinv,
                                             const unsigned short* __restrict__ hb,
                                             const float* __restrict__ bias,
                                             unsigned short* __restrict__ outb,
                                             float* __restrict__ outf) {
    int wid = (blockIdx.x * 256 + threadIdx.x) >> 6;
    int lane = threadIdx.x & 63;
    if (wid >= NN) return;
    float acc = bf2f(hb[(size_t)wid * HD + lane]);   // self loop (hs already dinv-scaled)
    int beg = rowptr[wid];
    int cnt = rowptr[wid + 1] - beg;
    for (int base = 0; base < cnt; base += 64) {
        int m = cnt - base; if (m > 64) m = 64;
        int sj = (lane < m) ? srcs[beg + base + lane] : 0;
        int j = 0;
        for (; j + 4 <= m; j += 4) {
            int s0 = __builtin_amdgcn_readlane(sj, j);
            int s1 = __builtin_amdgcn_readlane(sj, j + 1);
            int s2 = __builtin_amdgcn_readlane(sj, j + 2);
            int s3 = __builtin_amdgcn_readlane(sj, j + 3);
            float v0 = bf2f(hb[(size_t)s0 * HD + lane]);
            float v1 = bf2f(hb[(size_t)s1 * HD + lane]);
            float v2 = bf2f(hb[(size_t)s2 * HD + lane]);
            float v3 = bf2f(hb[(size_t)s3 * HD + lane]);
            acc += (v0 + v1) + (v2 + v3);
        }
        for (; j < m; ++j) {
            int s = __builtin_amdgcn_readlane(sj, j);
            acc += bf2f(hb[(size_t)s * HD + lane]);
        }
    }
    float dn = dinv[wid];
    acc *= dn;
    if (L1) {
        // store hs2 = dinv * relu(out + b1), bf16
        outb[(size_t)wid * HD + lane] = f2bf(fmaxf(acc + bias[lane], 0.f) * dn);
    } else {
        outf[(size_t)wid * HD + lane] = acc;
    }
}

// ---------- GEMM2 + bias: out = agg2 @ W2 + b2 ----------
__global__ __launch_bounds__(256) void k_gemm2(const float* __restrict__ h,
                                               const float* __restrict__ W2,
                                               const float* __restrict__ b2,
                                               float* __restrict__ out) {
    __shared__ float hs[32][65];
    __shared__ float ws2[64][40];
    const int t = threadIdx.x;
    const int r0 = blockIdx.x * 32;
    for (int i = t; i < 64 * OD; i += 256)
        ws2[i / OD][i % OD] = W2[i];
    for (int i = t; i < 32 * 64; i += 256) {
        int r = i >> 6, k = i & 63;
        hs[r][k] = h[(size_t)(r0 + r) * HD + k];
    }
    __syncthreads();
    for (int o = t; o < 32 * OD; o += 256) {
        int r = o / OD, c = o - r * OD;
        float s = 0.f;
        #pragma unroll
        for (int k = 0; k < HD; ++k)
            s = fmaf(hs[r][k], ws2[k][c], s);
        out[(size_t)(r0 + r) * OD + c] = s + b2[c];
    }
}

extern "C" void kernel_launch(void* const* d_in, const int* in_sizes, int n_in,
                              void* d_out, int out_size, void* d_ws, size_t ws_size,
                              hipStream_t stream) {
    const float* x  = (const float*)d_in[0];
    const float* W1 = (const float*)d_in[1];
    const float* b1 = (const float*)d_in[2];
    const float* W2 = (const float*)d_in[3];
    const float* b2 = (const float*)d_in[4];
    const void*  ei = d_in[5];
    float* out = (float*)d_out;

    // --- scratch carved out of d_out (16 MB); all dead before k_gemm2 writes out ---
    char* ob = (char*)d_out;
    int*   rowptr = (int*)ob;                              // 400,004 B
    int*   cnt    = (int*)(ob + 400896);                   // 400,000 B
    int*   bsum   = (int*)(ob + 801280);                   // 1,564 B
    int*   srcs   = (int*)(ob + 803328);                   // 6,400,000 B (end 7,203,328)
    float* dinv   = (float*)(ob + 7203840);                // 400,000 B (end 7,603,840)
    int*   rank   = (int*)(ob + 7604224);                  // 6,400,000 B (end 14,004,224)
    unsigned short* wh = (unsigned short*)(ob + 14004736); // 65,536 B
    unsigned short* wl = (unsigned short*)(ob + 14070272); // 65,536 B (end 14,135,808 < 16 MB)

    // --- ws: feature matrices (bf16 h, fp32 agg2) ---
    char* ws = (char*)d_ws;
    int*            flags  = (int*)ws;                         // 1 KB
    unsigned short* h1b    = (unsigned short*)(ws + 1024);     // 12.8 MB
    unsigned short* hrelub = (unsigned short*)(ws + 1024 + 12800000); // 12.8 MB
    float*          agg2   = (float*)(ws + 1024 + 25600000);   // 25.6 MB (end 51.2 MB)

    k_detect<<<1, 64, 0, stream>>>((const unsigned*)ei, flags);
    k_prepw<<<(KSTEPS * 4 * 64 + 255) / 256, 256, 0, stream>>>(W1, wh, wl);

    // CSR build: count(+rank) -> dinv -> scan -> scatter (atomic-free)
    hipMemsetAsync(cnt, 0, (size_t)NN * 4, stream);
    k_count<<<(NE / 4 + 255) / 256, 256, 0, stream>>>(ei, flags, cnt, rank);
    k_dinv<<<(NN + 255) / 256, 256, 0, stream>>>(cnt, dinv);
    k_scan_block<<<NBLK, 256, 0, stream>>>(cnt, rowptr, bsum);
    k_scan_bsum<<<1, 512, 0, stream>>>(bsum);
    k_scan_add<<<NBLK, 256, 0, stream>>>(rowptr, bsum);
    k_scatter<<<(NE / 4 + 255) / 256, 256, 0, stream>>>(ei, flags, rowptr, rank, srcs);

    // layer 1: MFMA GEMM (split-bf16, dinv-scaled bf16 output), then CSR aggregation
    k_gemm1m<<<(NN / 32 + 3) / 4, 256, 0, stream>>>(x, (const short8v*)wh, (const short8v*)wl, dinv, h1b);
    k_agg<true><<<(NN * 64) / 256, 256, 0, stream>>>(rowptr, srcs, dinv, h1b, b1, hrelub, (float*)nullptr);

    // layer 2: aggregate first (commutes with linear map), then GEMM+bias
    k_agg<false><<<(NN * 64) / 256, 256, 0, stream>>>(rowptr, srcs, dinv, hrelub, (const float*)nullptr, (unsigned short*)nullptr, agg2);
    k_gemm2<<<NN / 32, 256, 0, stream>>>(agg2, W2, b2, out);
}